// Round 12
// baseline (271.874 us; speedup 1.0000x reference)
//
#include <hip/hip_runtime.h>

typedef __attribute__((ext_vector_type(8))) _Float16 f16x8;   // 8 fp16 = 4 VGPRs
typedef __attribute__((ext_vector_type(2))) _Float16 h2;
typedef __attribute__((ext_vector_type(4))) float f32x4;
typedef __attribute__((ext_vector_type(16))) float f32x16;
typedef __attribute__((ext_vector_type(2))) unsigned u32x2;

constexpr int kC  = 128;
constexpr int kCH = 64;
constexpr int kN  = 4096;
constexpr float kLog2e = 1.4426950408889634f;

__device__ __forceinline__ unsigned pkrtz(float a, float b) {
    union { __fp16 __attribute__((ext_vector_type(2))) v; unsigned u; } cv;
    cv.v = __builtin_amdgcn_cvt_pkrtz(a, b);
    return cv.u;
}

__device__ __forceinline__ float x2(float x) {        // bare v_exp_f32
    return __builtin_amdgcn_exp2f(x);
}

__device__ __forceinline__ h2 uh(unsigned u) {        // bit-cast u32 -> fp16x2
    union { unsigned v; h2 h; } c; c.v = u; return c.h;
}

__device__ __forceinline__ u32x2 pl32(unsigned a, unsigned b) {
    return __builtin_amdgcn_permlane32_swap(a, b, false, false);
}
__device__ __forceinline__ u32x2 pl32x(float v) {     // xor-32 exchange of a scalar
    float c;
    asm("v_mov_b32 %0, %1" : "=&v"(c) : "v"(v));
    union { float f; unsigned u; } a, b2; a.f = v; b2.f = c;
    return pl32(a.u, b2.u);
}
__device__ __forceinline__ float uf(unsigned u) {
    union { unsigned v; float f; } c; c.v = u; return c.f;
}

// ---------------------------------------------------------------------------
// Fused projection — byte-identical to R4/R9 (validated anchor). Two slices:
//   0: tgt -> Q,G   1: ref -> K,V. 2 token-tiles/block, LDS double-buffered.
// ---------------------------------------------------------------------------
__global__ __launch_bounds__(256, 2) void proj_fused(
    const float* __restrict__ tgt, const float* __restrict__ ref,
    const float* __restrict__ Wt, const float* __restrict__ Wr,
    const float* __restrict__ Wo, const float* __restrict__ bt,
    const float* __restrict__ br, const float* __restrict__ bo,
    unsigned short* __restrict__ Qw, unsigned short* __restrict__ Kw,
    unsigned short* __restrict__ Vw, float* __restrict__ Gw)
{
    __shared__ __align__(16) unsigned short Xs[2][64 * 128];   // 2 x 16KB
    const int t = threadIdx.x;
    const int sl2 = blockIdx.y >> 3;         // 0 = tgt (Q+G), 1 = ref (K+V)
    const int b = blockIdx.y & 7;
    const int tok0 = blockIdx.x << 7;        // 128 tokens per block (2 tiles)

    const int w = t >> 6, lane = t & 63;
    const int lg = (lane >> 4) & 3, lm = lane & 15;

    const float* X = sl2 ? ref : tgt;
    const float* Xb0 = X + ((size_t)b * kC) * kN + tok0;
    unsigned short* Vout = Vw + ((size_t)b * kC) * kN + tok0;

    const float* Wqk  = sl2 ? Wr : Wt;
    const float* bqk  = sl2 ? br : bt;
    const float scale = sl2 ? 1.0f : kLog2e;

    f16x8 wfq[4];
    float bq[4];
    {
        const int ocb = w * 16;
        #pragma unroll
        for (int ks = 0; ks < 4; ++ks) {
            const float* wp = Wqk + (size_t)(ocb + lm) * kC + ks * 32 + lg * 8;
            f32x4 f0 = *(const f32x4*)wp;
            f32x4 f1 = *(const f32x4*)(wp + 4);
            union { f16x8 h; uint4 u; } cv;
            cv.u = make_uint4(pkrtz(f0[0] * scale, f0[1] * scale),
                              pkrtz(f0[2] * scale, f0[3] * scale),
                              pkrtz(f1[0] * scale, f1[1] * scale),
                              pkrtz(f1[2] * scale, f1[3] * scale));
            wfq[ks] = cv.h;
        }
        #pragma unroll
        for (int r = 0; r < 4; ++r) bq[r] = bqk[ocb + lg * 4 + r] * scale;
    }

    f16x8 wfg[2][4];
    float bg[2][4];
    if (sl2 == 0) {
        const int ocb = w * 32;
        #pragma unroll
        for (int ot = 0; ot < 2; ++ot) {
            const int oc = ocb + ot * 16 + lm;
            #pragma unroll
            for (int ks = 0; ks < 4; ++ks) {
                const float* wp = Wo + (size_t)oc * kC + ks * 32 + lg * 8;
                f32x4 f0 = *(const f32x4*)wp;
                f32x4 f1 = *(const f32x4*)(wp + 4);
                union { f16x8 h; uint4 u; } cv;
                cv.u = make_uint4(pkrtz(f0[0], f0[1]), pkrtz(f0[2], f0[3]),
                                  pkrtz(f1[0], f1[1]), pkrtz(f1[2], f1[3]));
                wfg[ot][ks] = cv.h;
            }
            #pragma unroll
            for (int r = 0; r < 4; ++r) bg[ot][r] = bo[ocb + ot * 16 + lg * 4 + r];
        }
    }

    const int tk4 = (t & 15) * 4;
    const int c8  = (t >> 4) * 8;

    auto loadX = [&](int toff, f32x4* xv) {
        #pragma unroll
        for (int j = 0; j < 8; ++j)
            xv[j] = *(const f32x4*)(Xb0 + (size_t)(c8 + j) * kN + toff + tk4);
    };
    auto stageX = [&](const f32x4* xv, unsigned short* Xsb, int toff) {
        if (sl2 == 1) {
            #pragma unroll
            for (int j = 0; j < 8; ++j)
                *(uint2*)(Vout + (size_t)(c8 + j) * kN + toff + tk4) =
                    make_uint2(pkrtz(xv[j][0], xv[j][1]), pkrtz(xv[j][2], xv[j][3]));
        }
        #pragma unroll
        for (int s = 0; s < 4; ++s) {        // s STATIC (rule #20)
            const int tok = tk4 + s;
            const int cc = (c8 >> 3) ^ (tok & 7);
            uint4 pk;
            pk.x = pkrtz(xv[0][s], xv[1][s]);
            pk.y = pkrtz(xv[2][s], xv[3][s]);
            pk.z = pkrtz(xv[4][s], xv[5][s]);
            pk.w = pkrtz(xv[6][s], xv[7][s]);
            *(uint4*)(Xsb + tok * 128 + cc * 8) = pk;
        }
    };
    auto compute = [&](const unsigned short* Xsb, int tokb) {
        unsigned short* outp = (sl2 ? Kw : Qw) + ((size_t)b * kN + tokb) * kCH;
        float* Gb = Gw + ((size_t)b * kC) * kN + tokb;
        const int ocq = w * 16;
        const int ocg = w * 32;
        #pragma unroll
        for (int ns = 0; ns < 4; ++ns) {
            const int tok = ns * 16 + lm;
            f16x8 xf[4];
            #pragma unroll
            for (int ks = 0; ks < 4; ++ks)
                xf[ks] = *(const f16x8*)(Xsb + tok * 128 +
                                         (((ks * 4 + lg) ^ (tok & 7)) << 3));
            {
                f32x4 acc = {bq[0], bq[1], bq[2], bq[3]};
                #pragma unroll
                for (int ks = 0; ks < 4; ++ks)
                    acc = __builtin_amdgcn_mfma_f32_16x16x32_f16(wfq[ks], xf[ks], acc, 0, 0, 0);
                uint2 pk;
                pk.x = pkrtz(fmaxf(acc[0], 0.f), fmaxf(acc[1], 0.f));
                pk.y = pkrtz(fmaxf(acc[2], 0.f), fmaxf(acc[3], 0.f));
                *(uint2*)(outp + (size_t)tok * kCH + ocq + lg * 4) = pk;
            }
            if (sl2 == 0) {
                #pragma unroll
                for (int ot = 0; ot < 2; ++ot) {
                    f32x4 acc = {bg[ot][0], bg[ot][1], bg[ot][2], bg[ot][3]};
                    #pragma unroll
                    for (int ks = 0; ks < 4; ++ks)
                        acc = __builtin_amdgcn_mfma_f32_16x16x32_f16(wfg[ot][ks], xf[ks], acc, 0, 0, 0);
                    #pragma unroll
                    for (int r = 0; r < 4; ++r)
                        Gb[(size_t)(ocg + ot * 16 + lg * 4 + r) * kN + tok] = acc[r];
                }
            }
        }
    };

    f32x4 xv[8], xw[8];
    loadX(0, xv);
    stageX(xv, Xs[0], 0);
    __syncthreads();
    loadX(64, xw);
    compute(Xs[0], tok0);
    stageX(xw, Xs[1], 64);
    __syncthreads();
    compute(Xs[1], tok0 + 64);
}

// ---------------------------------------------------------------------------
// Flash attention R11 (resubmitted unchanged after infra failure): all-register
// operand flow — NO LDS, NO BARRIERS in the main loop. K frags (16 VGPR) and
// V frags (32 VGPR) loaded global->reg one tile ahead (compiler emits counted
// vmcnt waits); each wave free-runs. 2 waves/SIMD -> 256 VGPR budget, ~220
// used. Keeps: 32x32 split-K wave pairs, defer-max (THR=8), permlane32
// exchanges, lagged PV. psum via v_pk_add_f16 tree. Per-lane addresses read
// exactly the bytes the LDS path delivered -> HBM/L2 traffic unchanged.
// ---------------------------------------------------------------------------
__global__ __launch_bounds__(256, 2) void flash13_kernel(
    const unsigned short* __restrict__ Qw,   // [8][4096][64] fp16 (x log2e)
    const unsigned short* __restrict__ Kw,   // [8][4096][64] fp16
    const unsigned short* __restrict__ Vw,   // [8][128][4096] fp16
    const float* __restrict__ Gw,            // [8][128][4096] fp32 gate
    float* __restrict__ out)                 // [8][128][4096]
{
    __shared__ __align__(16) float Obuf[8192];   // 32KB (epilogue merge only)
    __shared__ float2 mlb[4][32];                // 1KB

    const int t = threadIdx.x;
    const int b  = blockIdx.x & 7;           // XCD j serves batch j
    const int n0 = (blockIdx.x >> 3) << 6;
    const int w = t >> 6, lane = t & 63;
    const int qg = w >> 1, kh = w & 1;       // q-group, key-half
    const int lq = lane & 31, hh = lane >> 5;
    const int n0q = n0 + qg * 32 + lq;
    constexpr int NT = kN / 64;

    const unsigned short* Qb = Qw + ((size_t)b * kN + n0q) * kCH;
    // this lane's K row (key = m0 + kh*32+lq), d-offset hh*8
    const unsigned short* Kr = Kw + ((size_t)b * kN + kh * 32 + lq) * kCH + hh * 8;
    // this lane's V rows (c = cb*32+lq), key-offset kh*32 + hh*8
    const unsigned short* Vr = Vw + ((size_t)b * kC + lq) * (size_t)kN + kh * 32 + hh * 8;

    f16x8 qf[4];
    #pragma unroll
    for (int st = 0; st < 4; ++st)
        qf[st] = *(const f16x8*)(Qb + st * 16 + hh * 8);

    f32x16 O[4];
    #pragma unroll
    for (int cb = 0; cb < 4; ++cb)
        #pragma unroll
        for (int r = 0; r < 16; ++r) O[cb][r] = 0.f;
    float L = 0.f, m_run = 0.f;              // S >= 0 (relu inputs), exp2 domain

    f16x8 pfp[2];
    {
        union { uint4 u; f16x8 h; } z;
        z.u = make_uint4(0u, 0u, 0u, 0u);
        pfp[0] = z.h; pfp[1] = z.h;
    }

    auto loadK = [&](f16x8 (&Kd)[4], int m0) {
        #pragma unroll
        for (int st = 0; st < 4; ++st)
            Kd[st] = *(const f16x8*)(Kr + (size_t)m0 * kCH + st * 16);
    };
    auto loadV = [&](f16x8 (&Vd)[4][2], int m0) {
        #pragma unroll
        for (int cb = 0; cb < 4; ++cb)
            #pragma unroll
            for (int s = 0; s < 2; ++s)
                Vd[cb][s] = *(const f16x8*)(Vr + (size_t)cb * 32 * kN + m0 + s * 16);
    };

    f16x8 KA[4], KB[4], VA[4][2], VB[4][2];
    loadK(KA, 0);                            // K(0) in flight

    // tile body: uses K(t)=Kc (loaded last iter); issues V(t)->Vc and
    // K(t+1)->Kn; PV(t-1) on Vp (loaded last iter); P(t) -> pfp for next.
    auto tile = [&](f16x8 (&Kc)[4], f16x8 (&Kn)[4],
                    f16x8 (&Vc)[4][2], f16x8 (&Vp)[4][2], int kt) {
        const int m0 = kt << 6;
        loadV(Vc, m0);                       // V(t): consumed next iteration
        if (kt + 1 < NT) loadK(Kn, m0 + 64); // K(t+1)

        // ---- QK^T on prefetched K regs (vmcnt-counted wait, no barrier) ----
        f32x16 sa;
        #pragma unroll
        for (int r = 0; r < 16; ++r) sa[r] = 0.f;
        __builtin_amdgcn_s_setprio(1);
        #pragma unroll
        for (int st = 0; st < 4; ++st)
            sa = __builtin_amdgcn_mfma_f32_32x32x16_f16(Kc[st], qf[st], sa, 0, 0, 0);
        __builtin_amdgcn_s_setprio(0);

        // ---- max (pairwise tree + permlane swap) ----
        float m0a = fmaxf(fmaxf(sa[0], sa[1]), fmaxf(sa[2], sa[3]));
        float m0b = fmaxf(fmaxf(sa[4], sa[5]), fmaxf(sa[6], sa[7]));
        float m0c = fmaxf(fmaxf(sa[8], sa[9]), fmaxf(sa[10], sa[11]));
        float m0d = fmaxf(fmaxf(sa[12], sa[13]), fmaxf(sa[14], sa[15]));
        float mh = fmaxf(fmaxf(m0a, m0b), fmaxf(m0c, m0d));
        u32x2 mr = pl32x(mh);
        const float mq = fmaxf(uf(mr[0]), uf(mr[1]));
        const bool resc = __any(mq > m_run + 8.0f);   // defer-max THR=8
        const float mnew = resc ? fmaxf(m_run, mq) : m_run;

        // ---- PV(t-1): overlaps softmax(t)'s exp/pack ----
        __builtin_amdgcn_s_setprio(1);
        if (kt > 0) {
            #pragma unroll
            for (int cb = 0; cb < 4; ++cb) {
                #pragma unroll
                for (int s = 0; s < 2; ++s)
                    O[cb] = __builtin_amdgcn_mfma_f32_32x32x16_f16(Vp[cb][s], pfp[s], O[cb], 0, 0, 0);
            }
        }
        __builtin_amdgcn_s_setprio(0);

        // ---- exp / pack / rowsum (pk_add_f16 tree on ROUNDED P) ----
        #pragma unroll
        for (int r = 0; r < 16; ++r) sa[r] = x2(sa[r] - mnew);
        unsigned P[8];
        #pragma unroll
        for (int i = 0; i < 8; ++i) P[i] = pkrtz(sa[2 * i], sa[2 * i + 1]);
        h2 s0 = uh(P[0]) + uh(P[1]);
        h2 s1 = uh(P[2]) + uh(P[3]);
        h2 s2 = uh(P[4]) + uh(P[5]);
        h2 s3 = uh(P[6]) + uh(P[7]);
        s0 += s1; s2 += s3; s0 += s2;
        float ps = (float)s0[0] + (float)s0[1];
        u32x2 pr = pl32x(ps);
        ps = uf(pr[0]) + uf(pr[1]);

        if (resc) {                          // after PV(t-1): P(t-1) at old scale
            const float al = x2(m_run - mnew);
            #pragma unroll
            for (int cb = 0; cb < 4; ++cb) O[cb] *= al;
            L = L * al + ps;
            m_run = mnew;
        } else {
            L += ps;
        }

        // ---- P relayout -> pfp for NEXT tile (4 permlane swaps) ----
        #pragma unroll
        for (int s = 0; s < 2; ++s) {
            u32x2 r0 = pl32(P[4 * s + 0], P[4 * s + 2]);
            u32x2 r1 = pl32(P[4 * s + 1], P[4 * s + 3]);
            union { uint4 u; f16x8 h; } cv;
            cv.u = make_uint4(r0[0], r1[0], r0[1], r1[1]);
            pfp[s] = cv.h;
        }
    };

    for (int kt = 0; kt < NT; kt += 2) {
        tile(KA, KB, VA, VB, kt);            // even: K(t)=KA, V(t)->VA, PV on VB
        tile(KB, KA, VB, VA, kt + 1);        // odd : K(t)=KB, V(t)->VB, PV on VA
    }

    // ---- final PV (tile NT-1, odd -> V in VB, P in pfp) ----
    __builtin_amdgcn_s_setprio(1);
    #pragma unroll
    for (int cb = 0; cb < 4; ++cb) {
        #pragma unroll
        for (int s = 0; s < 2; ++s)
            O[cb] = __builtin_amdgcn_mfma_f32_32x32x16_f16(VB[cb][s], pfp[s], O[cb], 0, 0, 0);
    }
    __builtin_amdgcn_s_setprio(0);

    // ---- epilogue: split-K merge across the wave pair, gate, store ----
    __syncthreads();
    mlb[w][lq] = make_float2(m_run, L);      // lanes lq and lq+32 write same val
    __syncthreads();
    const float2 pml = mlb[w ^ 1][lq];
    const float mt = fmaxf(m_run, pml.x);
    const float a  = x2(m_run - mt);
    const float Lt = L * a + pml.y * x2(pml.x - mt);

    const int obase = qg * 4096 + lane * 64;
    #pragma unroll
    for (int cb = 0; cb < 4; ++cb) O[cb] *= a;

    if (kh) {                                // odd wave: publish scaled O
        #pragma unroll
        for (int c = 0; c < 16; ++c) {
            const int cb = c >> 2, q4 = c & 3;
            *(float4*)(Obuf + obase + (((c + lane) & 15) << 2)) =
                make_float4(O[cb][q4 * 4 + 0], O[cb][q4 * 4 + 1],
                            O[cb][q4 * 4 + 2], O[cb][q4 * 4 + 3]);
        }
    }
    __syncthreads();
    if (!kh) {                               // even wave: merge + gate + store
        #pragma unroll
        for (int c = 0; c < 16; ++c) {
            const int cb = c >> 2, q4 = c & 3;
            float4 p = *(const float4*)(Obuf + obase + (((c + lane) & 15) << 2));
            O[cb][q4 * 4 + 0] += p.x;
            O[cb][q4 * 4 + 1] += p.y;
            O[cb][q4 * 4 + 2] += p.z;
            O[cb][q4 * 4 + 3] += p.w;
        }
        const float inv = 1.0f / Lt;
        const float* Gb = Gw + ((size_t)b * kC + 4 * hh) * kN + n0 + qg * 32 + lq;
        float*       Ob = out + ((size_t)b * kC + 4 * hh) * kN + n0 + qg * 32 + lq;
        #pragma unroll
        for (int cb = 0; cb < 4; ++cb) {
            #pragma unroll
            for (int r = 0; r < 16; ++r) {
                const int coff = cb * 32 + (r & 3) + 8 * (r >> 2);
                Ob[(size_t)coff * kN] = O[cb][r] * inv * Gb[(size_t)coff * kN];
            }
        }
    }
}

// ---------------------------------------------------------------------------
extern "C" void kernel_launch(void* const* d_in, const int* in_sizes, int n_in,
                              void* d_out, int out_size, void* d_ws, size_t ws_size,
                              hipStream_t stream) {
    const float* tgt   = (const float*)d_in[0];
    const float* ref   = (const float*)d_in[1];
    const float* W_tgt = (const float*)d_in[2];
    const float* b_tgt = (const float*)d_in[3];
    const float* W_ref = (const float*)d_in[4];
    const float* b_ref = (const float*)d_in[5];
    const float* W_out = (const float*)d_in[6];
    const float* b_out = (const float*)d_in[7];
    float* out = (float*)d_out;

    const size_t QK = (size_t)8 * kN * kCH;              // fp16 -> 4 MB each
    const size_t CV = (size_t)8 * kC * kN;               // fp16 -> 8 MB
    unsigned short* Qw = (unsigned short*)d_ws;          // 4 MB
    unsigned short* Kw = Qw + QK;                        // 4 MB
    unsigned short* Vw = Kw + QK;                        // 8 MB
    float*          Gw = (float*)(Vw + CV);              // 16 MB (total 32 MB)

    proj_fused<<<dim3(32, 16), 256, 0, stream>>>(tgt, ref, W_tgt, W_ref, W_out,
                                                 b_tgt, b_ref, b_out, Qw, Kw, Vw, Gw);
    flash13_kernel<<<dim3(512), 256, 0, stream>>>(Qw, Kw, Vw, Gw, out);
}

// Round 13
// 163.682 us; speedup vs baseline: 1.6610x; 1.6610x over previous
//
#include <hip/hip_runtime.h>

typedef __attribute__((ext_vector_type(8))) _Float16 f16x8;   // 8 fp16 = 4 VGPRs
typedef __attribute__((ext_vector_type(2))) _Float16 h2;
typedef __attribute__((ext_vector_type(4))) float f32x4;
typedef __attribute__((ext_vector_type(16))) float f32x16;
typedef __attribute__((ext_vector_type(2))) unsigned u32x2;

constexpr int kC  = 128;
constexpr int kCH = 64;
constexpr int kN  = 4096;
constexpr float kLog2e = 1.4426950408889634f;

__device__ __forceinline__ unsigned pkrtz(float a, float b) {
    union { __fp16 __attribute__((ext_vector_type(2))) v; unsigned u; } cv;
    cv.v = __builtin_amdgcn_cvt_pkrtz(a, b);
    return cv.u;
}

__device__ __forceinline__ float x2(float x) {        // bare v_exp_f32
    return __builtin_amdgcn_exp2f(x);
}

__device__ __forceinline__ h2 uh(unsigned u) {        // bit-cast u32 -> fp16x2
    union { unsigned v; h2 h; } c; c.v = u; return c.h;
}

__device__ __forceinline__ u32x2 pl32(unsigned a, unsigned b) {
    return __builtin_amdgcn_permlane32_swap(a, b, false, false);
}
__device__ __forceinline__ u32x2 pl32x(float v) {     // xor-32 exchange of a scalar
    float c;
    asm("v_mov_b32 %0, %1" : "=&v"(c) : "v"(v));
    union { float f; unsigned u; } a, b2; a.f = v; b2.f = c;
    return pl32(a.u, b2.u);
}
__device__ __forceinline__ float uf(unsigned u) {
    union { unsigned v; float f; } c; c.v = u; return c.f;
}

// direct global->LDS DMA, 16B per lane, dest = wave-uniform base + lane*16
__device__ __forceinline__ void g2l16(const unsigned short* g, unsigned short* l) {
    __builtin_amdgcn_global_load_lds(
        (const __attribute__((address_space(1))) unsigned int*)(g),
        (__attribute__((address_space(3))) unsigned int*)(l),
        16, 0, 0);
}

// ---------------------------------------------------------------------------
// Fused projection — byte-identical to R4/R9 (validated anchor). Two slices:
//   0: tgt -> Q,G   1: ref -> K,V. 2 token-tiles/block, LDS double-buffered.
// ---------------------------------------------------------------------------
__global__ __launch_bounds__(256, 2) void proj_fused(
    const float* __restrict__ tgt, const float* __restrict__ ref,
    const float* __restrict__ Wt, const float* __restrict__ Wr,
    const float* __restrict__ Wo, const float* __restrict__ bt,
    const float* __restrict__ br, const float* __restrict__ bo,
    unsigned short* __restrict__ Qw, unsigned short* __restrict__ Kw,
    unsigned short* __restrict__ Vw, float* __restrict__ Gw)
{
    __shared__ __align__(16) unsigned short Xs[2][64 * 128];   // 2 x 16KB
    const int t = threadIdx.x;
    const int sl2 = blockIdx.y >> 3;         // 0 = tgt (Q+G), 1 = ref (K+V)
    const int b = blockIdx.y & 7;
    const int tok0 = blockIdx.x << 7;        // 128 tokens per block (2 tiles)

    const int w = t >> 6, lane = t & 63;
    const int lg = (lane >> 4) & 3, lm = lane & 15;

    const float* X = sl2 ? ref : tgt;
    const float* Xb0 = X + ((size_t)b * kC) * kN + tok0;
    unsigned short* Vout = Vw + ((size_t)b * kC) * kN + tok0;

    const float* Wqk  = sl2 ? Wr : Wt;
    const float* bqk  = sl2 ? br : bt;
    const float scale = sl2 ? 1.0f : kLog2e;

    f16x8 wfq[4];
    float bq[4];
    {
        const int ocb = w * 16;
        #pragma unroll
        for (int ks = 0; ks < 4; ++ks) {
            const float* wp = Wqk + (size_t)(ocb + lm) * kC + ks * 32 + lg * 8;
            f32x4 f0 = *(const f32x4*)wp;
            f32x4 f1 = *(const f32x4*)(wp + 4);
            union { f16x8 h; uint4 u; } cv;
            cv.u = make_uint4(pkrtz(f0[0] * scale, f0[1] * scale),
                              pkrtz(f0[2] * scale, f0[3] * scale),
                              pkrtz(f1[0] * scale, f1[1] * scale),
                              pkrtz(f1[2] * scale, f1[3] * scale));
            wfq[ks] = cv.h;
        }
        #pragma unroll
        for (int r = 0; r < 4; ++r) bq[r] = bqk[ocb + lg * 4 + r] * scale;
    }

    f16x8 wfg[2][4];
    float bg[2][4];
    if (sl2 == 0) {
        const int ocb = w * 32;
        #pragma unroll
        for (int ot = 0; ot < 2; ++ot) {
            const int oc = ocb + ot * 16 + lm;
            #pragma unroll
            for (int ks = 0; ks < 4; ++ks) {
                const float* wp = Wo + (size_t)oc * kC + ks * 32 + lg * 8;
                f32x4 f0 = *(const f32x4*)wp;
                f32x4 f1 = *(const f32x4*)(wp + 4);
                union { f16x8 h; uint4 u; } cv;
                cv.u = make_uint4(pkrtz(f0[0], f0[1]), pkrtz(f0[2], f0[3]),
                                  pkrtz(f1[0], f1[1]), pkrtz(f1[2], f1[3]));
                wfg[ot][ks] = cv.h;
            }
            #pragma unroll
            for (int r = 0; r < 4; ++r) bg[ot][r] = bo[ocb + ot * 16 + lg * 4 + r];
        }
    }

    const int tk4 = (t & 15) * 4;
    const int c8  = (t >> 4) * 8;

    auto loadX = [&](int toff, f32x4* xv) {
        #pragma unroll
        for (int j = 0; j < 8; ++j)
            xv[j] = *(const f32x4*)(Xb0 + (size_t)(c8 + j) * kN + toff + tk4);
    };
    auto stageX = [&](const f32x4* xv, unsigned short* Xsb, int toff) {
        if (sl2 == 1) {
            #pragma unroll
            for (int j = 0; j < 8; ++j)
                *(uint2*)(Vout + (size_t)(c8 + j) * kN + toff + tk4) =
                    make_uint2(pkrtz(xv[j][0], xv[j][1]), pkrtz(xv[j][2], xv[j][3]));
        }
        #pragma unroll
        for (int s = 0; s < 4; ++s) {        // s STATIC (rule #20)
            const int tok = tk4 + s;
            const int cc = (c8 >> 3) ^ (tok & 7);
            uint4 pk;
            pk.x = pkrtz(xv[0][s], xv[1][s]);
            pk.y = pkrtz(xv[2][s], xv[3][s]);
            pk.z = pkrtz(xv[4][s], xv[5][s]);
            pk.w = pkrtz(xv[6][s], xv[7][s]);
            *(uint4*)(Xsb + tok * 128 + cc * 8) = pk;
        }
    };
    auto compute = [&](const unsigned short* Xsb, int tokb) {
        unsigned short* outp = (sl2 ? Kw : Qw) + ((size_t)b * kN + tokb) * kCH;
        float* Gb = Gw + ((size_t)b * kC) * kN + tokb;
        const int ocq = w * 16;
        const int ocg = w * 32;
        #pragma unroll
        for (int ns = 0; ns < 4; ++ns) {
            const int tok = ns * 16 + lm;
            f16x8 xf[4];
            #pragma unroll
            for (int ks = 0; ks < 4; ++ks)
                xf[ks] = *(const f16x8*)(Xsb + tok * 128 +
                                         (((ks * 4 + lg) ^ (tok & 7)) << 3));
            {
                f32x4 acc = {bq[0], bq[1], bq[2], bq[3]};
                #pragma unroll
                for (int ks = 0; ks < 4; ++ks)
                    acc = __builtin_amdgcn_mfma_f32_16x16x32_f16(wfq[ks], xf[ks], acc, 0, 0, 0);
                uint2 pk;
                pk.x = pkrtz(fmaxf(acc[0], 0.f), fmaxf(acc[1], 0.f));
                pk.y = pkrtz(fmaxf(acc[2], 0.f), fmaxf(acc[3], 0.f));
                *(uint2*)(outp + (size_t)tok * kCH + ocq + lg * 4) = pk;
            }
            if (sl2 == 0) {
                #pragma unroll
                for (int ot = 0; ot < 2; ++ot) {
                    f32x4 acc = {bg[ot][0], bg[ot][1], bg[ot][2], bg[ot][3]};
                    #pragma unroll
                    for (int ks = 0; ks < 4; ++ks)
                        acc = __builtin_amdgcn_mfma_f32_16x16x32_f16(wfg[ot][ks], xf[ks], acc, 0, 0, 0);
                    #pragma unroll
                    for (int r = 0; r < 4; ++r)
                        Gb[(size_t)(ocg + ot * 16 + lg * 4 + r) * kN + tok] = acc[r];
                }
            }
        }
    };

    f32x4 xv[8], xw[8];
    loadX(0, xv);
    stageX(xv, Xs[0], 0);
    __syncthreads();
    loadX(64, xw);
    compute(Xs[0], tok0);
    stageX(xw, Xs[1], 64);
    __syncthreads();
    compute(Xs[1], tok0 + 64);
}

// ---------------------------------------------------------------------------
// Flash attention R13: flash12's validated 32x32 split-K machine widened to
// 512-thread blocks / 128 q-rows (4 wave-pairs). Each staged K/V tile now
// feeds 2x the q-rows -> grid-total L2->LDS staging traffic HALVES (the
// measured ~875cyc/tile co-dominant floor), and occupancy doubles to
// 4 waves/SIMD (16 waves/CU, 2 blocks/CU, 132KB LDS). All math, swizzles,
// defer-max, permlane exchanges, lagged-PV V-triple-buffer: flash12 verbatim.
// ---------------------------------------------------------------------------
__global__ __launch_bounds__(512, 4) void flash14_kernel(
    const unsigned short* __restrict__ Qw,   // [8][4096][64] fp16 (x log2e)
    const unsigned short* __restrict__ Kw,   // [8][4096][64] fp16
    const unsigned short* __restrict__ Vw,   // [8][128][4096] fp16
    const float* __restrict__ Gw,            // [8][128][4096] fp32 gate
    float* __restrict__ out)                 // [8][128][4096]
{
    // flat LDS: Ks0 8K | Ks1 8K | Vs0 16K | Vs1 16K | Vs2 16K | mlb 2K = 66KB
    __shared__ __align__(16) unsigned char SM[67584];

    const int t = threadIdx.x;
    const int b  = blockIdx.x & 7;           // XCD j serves batch j
    const int n0 = (blockIdx.x >> 3) << 7;   // 128 q-rows per block
    const int w = t >> 6, lane = t & 63;     // w: 0..7
    const int qg = w >> 1, kh = w & 1;       // q-group (0..3), key-half
    const int lq = lane & 31, hh = lane >> 5;
    const int n0q = n0 + qg * 32 + lq;
    constexpr int NT = kN / 64;

    const unsigned short* Qb = Qw + ((size_t)b * kN + n0q) * kCH;
    const unsigned short* Kb = Kw + ((size_t)b * kN) * kCH;
    const unsigned short* Vb = Vw + ((size_t)b * kC) * kN;

    f16x8 qf[4];
    #pragma unroll
    for (int st = 0; st < 4; ++st)
        qf[st] = *(const f16x8*)(Qb + st * 16 + hh * 8);

    // staging geometry: 512 threads cover K(64x64) + V(128x64) per tile.
    // srow = t>>3 (0..63), chunk scol = t&7; involution matches read swizzle.
    const int srow = t >> 3, scol = t & 7;
    const int sco  = (scol ^ (srow & 7)) << 3;
    const int wv   = t >> 6;                 // 0..7

    int ka[4];
    #pragma unroll
    for (int st = 0; st < 4; ++st)
        ka[st] = (kh * 32 + lq) * 64 + (((2 * st + hh) ^ (lq & 7)) << 3);
    int va[4][2];
    #pragma unroll
    for (int cb = 0; cb < 4; ++cb)
        #pragma unroll
        for (int s = 0; s < 2; ++s)
            va[cb][s] = (cb * 32 + lq) * 64 + (((kh * 4 + 2 * s + hh) ^ (lq & 7)) << 3);

    f32x16 O[4];
    #pragma unroll
    for (int cb = 0; cb < 4; ++cb)
        #pragma unroll
        for (int r = 0; r < 16; ++r) O[cb][r] = 0.f;
    float L = 0.f, m_run = 0.f;              // S >= 0 (relu inputs), exp2 domain

    f16x8 pfp[2];
    {
        union { uint4 u; f16x8 h; } z;
        z.u = make_uint4(0u, 0u, 0u, 0u);
        pfp[0] = z.h; pfp[1] = z.h;
    }

    auto stage = [&](unsigned short* Kd, unsigned short* Vd, int m0) {
        g2l16(Kb + (size_t)(m0 + srow) * kCH + sco, Kd + wv * 512);
        #pragma unroll
        for (int j = 0; j < 2; ++j)
            g2l16(Vb + (size_t)(64 * j + srow) * kN + m0 + sco,
                  Vd + j * 4096 + wv * 512);
    };

    unsigned short *Kt = (unsigned short*)SM;
    unsigned short *Kn = (unsigned short*)(SM + 8192);
    unsigned short *Vp = (unsigned short*)(SM + 49152);  // Vs2
    unsigned short *Vt = (unsigned short*)(SM + 16384);  // Vs0
    unsigned short *Vn = (unsigned short*)(SM + 32768);  // Vs1
    stage(Kt, Vt, 0);                        // prologue: tile 0

    for (int kt = 0; kt < NT; ++kt) {
        __syncthreads();                     // staged tile kt ready
        if (kt + 1 < NT) stage(Kn, Vn, (kt + 1) << 6);

        // ---- QK^T: S (32 keys x 32 q), keys = this wave's half ----
        f32x16 sa;
        #pragma unroll
        for (int r = 0; r < 16; ++r) sa[r] = 0.f;
        __builtin_amdgcn_s_setprio(1);
        #pragma unroll
        for (int st = 0; st < 4; ++st) {
            f16x8 kf = *(const f16x8*)(Kt + ka[st]);
            sa = __builtin_amdgcn_mfma_f32_32x32x16_f16(kf, qf[st], sa, 0, 0, 0);
        }
        __builtin_amdgcn_s_setprio(0);

        // ---- max (pairwise tree + permlane swap) ----
        float m0a = fmaxf(fmaxf(sa[0], sa[1]), fmaxf(sa[2], sa[3]));
        float m0b = fmaxf(fmaxf(sa[4], sa[5]), fmaxf(sa[6], sa[7]));
        float m0c = fmaxf(fmaxf(sa[8], sa[9]), fmaxf(sa[10], sa[11]));
        float m0d = fmaxf(fmaxf(sa[12], sa[13]), fmaxf(sa[14], sa[15]));
        float mh = fmaxf(fmaxf(m0a, m0b), fmaxf(m0c, m0d));
        u32x2 mr = pl32x(mh);
        const float mq = fmaxf(uf(mr[0]), uf(mr[1]));
        const bool resc = __any(mq > m_run + 8.0f);   // defer-max THR=8
        const float mnew = resc ? fmaxf(m_run, mq) : m_run;

        // ---- PV(t-1): overlaps softmax(t)'s exp/pack ----
        __builtin_amdgcn_s_setprio(1);
        if (kt > 0) {
            #pragma unroll
            for (int cb = 0; cb < 4; ++cb) {
                #pragma unroll
                for (int s = 0; s < 2; ++s) {
                    f16x8 vf = *(const f16x8*)(Vp + va[cb][s]);
                    O[cb] = __builtin_amdgcn_mfma_f32_32x32x16_f16(vf, pfp[s], O[cb], 0, 0, 0);
                }
            }
        }
        __builtin_amdgcn_s_setprio(0);

        // ---- exp / pack / rowsum (pk_add_f16 tree on ROUNDED P) ----
        #pragma unroll
        for (int r = 0; r < 16; ++r) sa[r] = x2(sa[r] - mnew);
        unsigned P[8];
        #pragma unroll
        for (int i = 0; i < 8; ++i) P[i] = pkrtz(sa[2 * i], sa[2 * i + 1]);
        h2 s0 = uh(P[0]) + uh(P[1]);
        h2 s1 = uh(P[2]) + uh(P[3]);
        h2 s2 = uh(P[4]) + uh(P[5]);
        h2 s3 = uh(P[6]) + uh(P[7]);
        s0 += s1; s2 += s3; s0 += s2;
        float ps = (float)s0[0] + (float)s0[1];
        u32x2 pr = pl32x(ps);
        ps = uf(pr[0]) + uf(pr[1]);

        if (resc) {                          // after PV(t-1): P(t-1) at old scale
            const float al = x2(m_run - mnew);
            #pragma unroll
            for (int cb = 0; cb < 4; ++cb) O[cb] *= al;
            L = L * al + ps;
            m_run = mnew;
        } else {
            L += ps;
        }

        // ---- P relayout -> pfp for NEXT tile (4 permlane swaps) ----
        #pragma unroll
        for (int s = 0; s < 2; ++s) {
            u32x2 r0 = pl32(P[4 * s + 0], P[4 * s + 2]);
            u32x2 r1 = pl32(P[4 * s + 1], P[4 * s + 3]);
            union { uint4 u; f16x8 h; } cv;
            cv.u = make_uint4(r0[0], r1[0], r0[1], r1[1]);
            pfp[s] = cv.h;
        }

        // ---- rotate buffers: V mod-3, K mod-2 ----
        unsigned short* tv = Vp; Vp = Vt; Vt = Vn; Vn = tv;
        unsigned short* tk = Kt; Kt = Kn; Kn = tk;
    }

    // ---- final PV (tile NT-1 -> V in Vp, P in pfp) ----
    __builtin_amdgcn_s_setprio(1);
    #pragma unroll
    for (int cb = 0; cb < 4; ++cb) {
        #pragma unroll
        for (int s = 0; s < 2; ++s) {
            f16x8 vf = *(const f16x8*)(Vp + va[cb][s]);
            O[cb] = __builtin_amdgcn_mfma_f32_32x32x16_f16(vf, pfp[s], O[cb], 0, 0, 0);
        }
    }
    __builtin_amdgcn_s_setprio(0);

    // ---- epilogue: split-K merge across each wave pair, gate, store ----
    float2* mlb = (float2*)(SM + 65536);     // [8][32]
    __syncthreads();
    mlb[w * 32 + lq] = make_float2(m_run, L);
    __syncthreads();
    const float2 pml = mlb[(w ^ 1) * 32 + lq];
    const float mt = fmaxf(m_run, pml.x);
    const float a  = x2(m_run - mt);
    const float Lt = L * a + pml.y * x2(pml.x - mt);

    float* Obuf = (float*)SM;                // overlays dead K+V buffers (64KB)
    const int obase = qg * 4096 + lane * 64;
    #pragma unroll
    for (int cb = 0; cb < 4; ++cb) O[cb] *= a;

    if (kh) {                                // odd wave of pair: publish scaled O
        #pragma unroll
        for (int c = 0; c < 16; ++c) {
            const int cb = c >> 2, q4 = c & 3;
            *(float4*)(Obuf + obase + (((c + lane) & 15) << 2)) =
                make_float4(O[cb][q4 * 4 + 0], O[cb][q4 * 4 + 1],
                            O[cb][q4 * 4 + 2], O[cb][q4 * 4 + 3]);
        }
    }
    __syncthreads();
    if (!kh) {                               // even wave: merge + gate + store
        #pragma unroll
        for (int c = 0; c < 16; ++c) {
            const int cb = c >> 2, q4 = c & 3;
            float4 p = *(const float4*)(Obuf + obase + (((c + lane) & 15) << 2));
            O[cb][q4 * 4 + 0] += p.x;
            O[cb][q4 * 4 + 1] += p.y;
            O[cb][q4 * 4 + 2] += p.z;
            O[cb][q4 * 4 + 3] += p.w;
        }
        const float inv = 1.0f / Lt;
        const float* Gb = Gw + ((size_t)b * kC + 4 * hh) * kN + n0 + qg * 32 + lq;
        float*       Ob = out + ((size_t)b * kC + 4 * hh) * kN + n0 + qg * 32 + lq;
        #pragma unroll
        for (int cb = 0; cb < 4; ++cb) {
            #pragma unroll
            for (int r = 0; r < 16; ++r) {
                const int coff = cb * 32 + (r & 3) + 8 * (r >> 2);
                Ob[(size_t)coff * kN] = O[cb][r] * inv * Gb[(size_t)coff * kN];
            }
        }
    }
}

// ---------------------------------------------------------------------------
extern "C" void kernel_launch(void* const* d_in, const int* in_sizes, int n_in,
                              void* d_out, int out_size, void* d_ws, size_t ws_size,
                              hipStream_t stream) {
    const float* tgt   = (const float*)d_in[0];
    const float* ref   = (const float*)d_in[1];
    const float* W_tgt = (const float*)d_in[2];
    const float* b_tgt = (const float*)d_in[3];
    const float* W_ref = (const float*)d_in[4];
    const float* b_ref = (const float*)d_in[5];
    const float* W_out = (const float*)d_in[6];
    const float* b_out = (const float*)d_in[7];
    float* out = (float*)d_out;

    const size_t QK = (size_t)8 * kN * kCH;              // fp16 -> 4 MB each
    const size_t CV = (size_t)8 * kC * kN;               // fp16 -> 8 MB
    unsigned short* Qw = (unsigned short*)d_ws;          // 4 MB
    unsigned short* Kw = Qw + QK;                        // 4 MB
    unsigned short* Vw = Kw + QK;                        // 8 MB
    float*          Gw = (float*)(Vw + CV);              // 16 MB (total 32 MB)

    proj_fused<<<dim3(32, 16), 256, 0, stream>>>(tgt, ref, W_tgt, W_ref, W_out,
                                                 b_tgt, b_ref, b_out, Qw, Kw, Vw, Gw);
    flash14_kernel<<<dim3(256), 512, 0, stream>>>(Qw, Kw, Vw, Gw, out);
}